// Round 12
// baseline (520.499 us; speedup 1.0000x reference)
//
#include <hip/hip_runtime.h>
#include <cfloat>

#define N_NODES 50000
#define N_EDGES 1600000
#define DX      128
#define DH      64
#define KH      4
#define NC      256                   // KH*DH
#define NEG_SLOPE 0.01f
#define SCAN_BLOCKS 196               // ceil(N_NODES/256); also bucket count (dst>>8)
#define BIN_BLOCKS 250
#define BIN_CHUNK  6400               // 250*6400 = 1.6M edges exactly

// ---------- setup: cnt=1 (self-loop pre-count), zero colsum, transpose Ww ----------
__global__ void k_setup(const float* __restrict__ Ww, float* __restrict__ Wt,
                        int* __restrict__ cnt, float* __restrict__ colsum) {
    int i = blockIdx.x * 256 + threadIdx.x;
    if (i < N_NODES) cnt[i] = 1;               // every node gets one self-loop
    if (i < NC) colsum[i] = 0.f;
    if (i < DX * NC) {
        int d = i >> 8, c = i & 255;
        Wt[d * NC + c] = Ww[c * DX + d];
    }
}

__device__ __forceinline__ unsigned pack_bf16(float a, float b) {
    unsigned ua = __float_as_uint(a), ub = __float_as_uint(b);
    ua = (ua + 0x7FFFu + ((ua >> 16) & 1u)) >> 16;          // RNE
    ub = (ub + 0x7FFFu + ((ub >> 16) & 1u)) & 0xFFFF0000u;
    return ua | ub;
}

// ---------- Wx GEMM + fused epilogue: bf16 Wx copy + (s, e^s, e^.01s) tables ----------
__global__ void __launch_bounds__(256) k_gemm1(const float* __restrict__ x,
                                               const float* __restrict__ Wt,
                                               const float* __restrict__ Wb,
                                               const float* __restrict__ aw,
                                               const float* __restrict__ ab,
                                               uint2* __restrict__ Wxb,
                                               float4* __restrict__ Si4,
                                               float4* __restrict__ Sj4) {
    // readfirstlane: wave index provably uniform -> x row loads become s_load
    int wave = blockIdx.x * 4 + __builtin_amdgcn_readfirstlane(threadIdx.x >> 6);
    if (wave >= N_NODES / 8) return;           // 50000 % 8 == 0
    int lane = threadIdx.x & 63;
    int kh = lane >> 4, lq = lane & 15;
    int n0 = wave * 8;
    const float4* WtV = (const float4*)Wt;
    float acc[8][4];
#pragma unroll
    for (int r = 0; r < 8; ++r)
#pragma unroll
        for (int q = 0; q < 4; ++q) acc[r][q] = 0.f;

    for (int d = 0; d < DX; d += 4) {
        float xr[8][4];
#pragma unroll
        for (int r = 0; r < 8; ++r) {
            float4 v = *(const float4*)&x[(size_t)(n0 + r) * DX + d];
            xr[r][0] = v.x; xr[r][1] = v.y; xr[r][2] = v.z; xr[r][3] = v.w;
        }
#pragma unroll
        for (int q = 0; q < 4; ++q) {
            float4 wv = WtV[(size_t)(d + q) * 64 + lane];
#pragma unroll
            for (int r = 0; r < 8; ++r) {
                acc[r][0] += xr[r][q] * wv.x;
                acc[r][1] += xr[r][q] * wv.y;
                acc[r][2] += xr[r][q] * wv.z;
                acc[r][3] += xr[r][q] * wv.w;
            }
        }
    }
    float4 bias = ((const float4*)Wb)[lane];
    const float* awi = aw + kh * 2 * DH + lq * 4;
    const float* awj = awi + DH;
    float ai0 = awi[0], ai1 = awi[1], ai2 = awi[2], ai3 = awi[3];
    float aj0 = awj[0], aj1 = awj[1], aj2 = awj[2], aj3 = awj[3];
    float abk = ab[kh];
#pragma unroll
    for (int r = 0; r < 8; ++r) {
        float o0 = acc[r][0] + bias.x, o1 = acc[r][1] + bias.y;
        float o2 = acc[r][2] + bias.z, o3 = acc[r][3] + bias.w;
        uint2 pk; pk.x = pack_bf16(o0, o1); pk.y = pack_bf16(o2, o3);
        Wxb[(size_t)(n0 + r) * 64 + lane] = pk;
        float pi = o0 * ai0 + o1 * ai1 + o2 * ai2 + o3 * ai3;
        float pj = o0 * aj0 + o1 * aj1 + o2 * aj2 + o3 * aj3;
#pragma unroll
        for (int off = 8; off >= 1; off >>= 1) {
            pi += __shfl_xor(pi, off, 64);
            pj += __shfl_xor(pj, off, 64);
        }
        if (lq == 0) {
            float si = pi + abk;       // fold ab into dst-side score
            Si4[(n0 + r) * 4 + kh] = make_float4(si, __expf(si), __expf(0.01f * si), 0.f);
            Sj4[(n0 + r) * 4 + kh] = make_float4(pj, __expf(pj), __expf(0.01f * pj), 0.f);
        }
    }
}

// ---------- CSR build: real edges only (self loops pre-placed by k_fill) ----------
__global__ void k_hist(const int* __restrict__ ei, int* __restrict__ cnt) {
    const int4* dst4 = (const int4*)(ei + N_EDGES);
    int stride = gridDim.x * blockDim.x;
    for (int e = blockIdx.x * blockDim.x + threadIdx.x; e < N_EDGES / 4; e += stride) {
        int4 d = dst4[e];
        atomicAdd(&cnt[d.x], 1);
        atomicAdd(&cnt[d.y], 1);
        atomicAdd(&cnt[d.z], 1);
        atomicAdd(&cnt[d.w], 1);
    }
}

// ---------- scan phase 1: per-block sums ----------
__global__ void __launch_bounds__(256) k_blocksum(const int* __restrict__ cnt,
                                                  int* __restrict__ bsum) {
    __shared__ int part[4];
    int i = blockIdx.x * 256 + threadIdx.x;
    int v = (i < N_NODES) ? cnt[i] : 0;
#pragma unroll
    for (int off = 32; off >= 1; off >>= 1) v += __shfl_down(v, off, 64);
    if ((threadIdx.x & 63) == 0) part[threadIdx.x >> 6] = v;
    __syncthreads();
    if (threadIdx.x == 0)
        bsum[blockIdx.x] = part[0] + part[1] + part[2] + part[3];
}

// ---------- scan phase 2 (fused): block-prefix + in-block scan + CSR init ----------
// also initializes the per-bucket binning cursor: bcur[b] = rowstart[256b] - 256b
__global__ void __launch_bounds__(256) k_fill(const int* __restrict__ cnt,
                                              const int* __restrict__ bsum,
                                              int* __restrict__ rowstart,
                                              int* __restrict__ bcur,
                                              int* __restrict__ csr_src) {
    __shared__ int s[256];
    int t = threadIdx.x;
    int bv = (t < SCAN_BLOCKS) ? bsum[t] : 0;
    s[t] = bv;
    __syncthreads();
#pragma unroll
    for (int off = 1; off < 256; off <<= 1) {
        int u = (t >= off) ? s[t - off] : 0;
        __syncthreads();
        s[t] += u;
        __syncthreads();
    }
    int bpre = (blockIdx.x == 0) ? 0 : s[blockIdx.x - 1];
    int total = s[SCAN_BLOCKS - 1];
    __syncthreads();

    if (t == 0) bcur[blockIdx.x] = bpre - 256 * blockIdx.x;   // edges-only base

    int i = blockIdx.x * 256 + t;
    int v = (i < N_NODES) ? cnt[i] : 0;
    s[t] = v;
    __syncthreads();
#pragma unroll
    for (int off = 1; off < 256; off <<= 1) {
        int u = (t >= off) ? s[t - off] : 0;
        __syncthreads();
        s[t] += u;
        __syncthreads();
    }
    if (i < N_NODES) {
        int rs = bpre + s[t] - v;
        rowstart[i] = rs;
        csr_src[rs] = i * 64;      // self-loop first; pre-scaled (uint2-row index)
    }
    if (blockIdx.x == SCAN_BLOCKS - 1 && t == 0) rowstart[N_NODES] = total;
}

// ---------- binning pass: edges -> 196 dst-buckets, dense chunked writes ----------
__global__ void __launch_bounds__(256) k_bin(const int* __restrict__ ei,
                                             int* __restrict__ bcur,
                                             unsigned* __restrict__ binned) {
    __shared__ int bh[SCAN_BLOCKS];   // count, then local cursor
    __shared__ int bb[SCAN_BLOCKS];   // reserved global base
    int t = threadIdx.x;
    if (t < SCAN_BLOCKS) bh[t] = 0;
    __syncthreads();
    int e0 = blockIdx.x * BIN_CHUNK;
#pragma unroll 5
    for (int k = 0; k < BIN_CHUNK / 256; ++k) {
        int dst = ei[N_EDGES + e0 + t + k * 256];
        atomicAdd(&bh[dst >> 8], 1);
    }
    __syncthreads();
    if (t < SCAN_BLOCKS) {
        bb[t] = atomicAdd(&bcur[t], bh[t]);
        bh[t] = 0;
    }
    __syncthreads();
#pragma unroll 5
    for (int k = 0; k < BIN_CHUNK / 256; ++k) {
        int e = e0 + t + k * 256;
        int src = ei[e];
        int dst = ei[N_EDGES + e];
        int b = dst >> 8;
        int lo = atomicAdd(&bh[b], 1);
        binned[bb[b] + lo] = (unsigned)src | ((unsigned)(dst & 255) << 16);   // src < 2^16
    }
}

// ---------- final scatter: block per bucket, LDS cursors, pre-scaled src ----------
__global__ void __launch_bounds__(256) k_scatter2(const unsigned* __restrict__ binned,
                                                  const int* __restrict__ rowstart,
                                                  int* __restrict__ csr_src) {
    __shared__ int lcur[256];
    int t = threadIdx.x;
    int b = blockIdx.x;
    int d = b * 256 + t;
    lcur[t] = (d < N_NODES) ? rowstart[d] + 1 : 0;   // +1: skip self-loop slot
    int db0 = b * 256;
    int db1 = min(db0 + 256, N_NODES);
    int ebase = rowstart[db0] - db0;
    int eend  = rowstart[db1] - db1;
    __syncthreads();
    for (int i = ebase + t; i < eend; i += 256) {
        unsigned u = binned[i];
        int pos = atomicAdd(&lcur[u >> 16], 1);
        csr_src[pos] = (int)(u & 0xFFFFu) << 6;      // src*64 pre-scaled
    }
}

// ---------- aggregation: exp-free edge loop, scalarized control, MLP x16 ----------
__global__ void __launch_bounds__(256) k_aggregate(const int* __restrict__ rowstart,
                                                   const int* __restrict__ csr_src,
                                                   const float4* __restrict__ Si4,
                                                   const float4* __restrict__ Sj4,
                                                   const uint2* __restrict__ Wxb,
                                                   uint2* __restrict__ expb) {
    // readfirstlane: dst/i0/i1 provably wave-uniform -> rowstart & csr_src via s_load
    int dst = blockIdx.x * 4 + __builtin_amdgcn_readfirstlane(threadIdx.x >> 6);
    int lane = threadIdx.x & 63;
    int kh = lane >> 4;
    int i0 = rowstart[dst], i1 = rowstart[dst + 1];
    float4 si4 = Si4[dst * 4 + kh];
    float si = si4.x, EiP = si4.y, EiN = si4.z;   // exp(si), exp(.01 si)

    float den = 0.f, a0 = 0.f, a1 = 0.f, a2 = 0.f, a3 = 0.f;
    int i = i0;
    for (; i + 16 <= i1; i += 16) {
        int vv[16]; uint2 gg[16]; float ex[16];
#pragma unroll
        for (int u = 0; u < 16; ++u) vv[u] = csr_src[i + u];        // s_load (uniform)
#pragma unroll
        for (int u = 0; u < 16; ++u) gg[u] = Wxb[(size_t)vv[u] + lane];
#pragma unroll
        for (int u = 0; u < 16; ++u) {
            float4 s4 = Sj4[(vv[u] >> 4) + kh];
            float e = si + s4.x;
            ex[u] = (e >= 0.f ? EiP : EiN) * (e >= 0.f ? s4.y : s4.z);
        }
#pragma unroll
        for (int u = 0; u < 16; ++u) {
            float xv = ex[u];
            den += xv;
            a0 += xv * __uint_as_float(gg[u].x << 16);
            a1 += xv * __uint_as_float(gg[u].x & 0xFFFF0000u);
            a2 += xv * __uint_as_float(gg[u].y << 16);
            a3 += xv * __uint_as_float(gg[u].y & 0xFFFF0000u);
        }
    }
    for (; i + 4 <= i1; i += 4) {
        int vv[4]; uint2 gg[4]; float ex[4];
#pragma unroll
        for (int u = 0; u < 4; ++u) vv[u] = csr_src[i + u];
#pragma unroll
        for (int u = 0; u < 4; ++u) gg[u] = Wxb[(size_t)vv[u] + lane];
#pragma unroll
        for (int u = 0; u < 4; ++u) {
            float4 s4 = Sj4[(vv[u] >> 4) + kh];
            float e = si + s4.x;
            ex[u] = (e >= 0.f ? EiP : EiN) * (e >= 0.f ? s4.y : s4.z);
        }
#pragma unroll
        for (int u = 0; u < 4; ++u) {
            float xv = ex[u];
            den += xv;
            a0 += xv * __uint_as_float(gg[u].x << 16);
            a1 += xv * __uint_as_float(gg[u].x & 0xFFFF0000u);
            a2 += xv * __uint_as_float(gg[u].y << 16);
            a3 += xv * __uint_as_float(gg[u].y & 0xFFFF0000u);
        }
    }
    for (; i < i1; ++i) {
        int v = csr_src[i];
        uint2 g = Wxb[(size_t)v + lane];
        float4 s4 = Sj4[(v >> 4) + kh];
        float e = si + s4.x;
        float xv = (e >= 0.f ? EiP : EiN) * (e >= 0.f ? s4.y : s4.z);
        den += xv;
        a0 += xv * __uint_as_float(g.x << 16);
        a1 += xv * __uint_as_float(g.x & 0xFFFF0000u);
        a2 += xv * __uint_as_float(g.y << 16);
        a3 += xv * __uint_as_float(g.y & 0xFFFF0000u);
    }
    float r = 1.f / den;
    float e0 = __expf(a0 * r), e1 = __expf(a1 * r);
    float e2 = __expf(a2 * r), e3 = __expf(a3 * r);
    uint2 pk; pk.x = pack_bf16(e0, e1); pk.y = pack_bf16(e2, e3);
    expb[(size_t)dst * 64 + lane] = pk;          // bf16 exp(agg), cols 4l..4l+3
}

// ---------- column sums of exp(agg), uint2 loads (4 cols/thread) ----------
__global__ void __launch_bounds__(256) k_colsum(const uint2* __restrict__ expb,
                                                float* __restrict__ colsum) {
    int tid = threadIdx.x;
    int cp = tid & 63;             // uint2 index within row (cols 4cp..4cp+3)
    int ro = tid >> 6;             // 0..3 row offset
    int base = blockIdx.x * 250;
    int r1 = min(base + 250, N_NODES);
    float s0 = 0.f, s1 = 0.f, s2 = 0.f, s3 = 0.f;
    for (int r = base + ro; r < r1; r += 4) {
        uint2 u = expb[(size_t)r * 64 + cp];
        s0 += __uint_as_float(u.x << 16);
        s1 += __uint_as_float(u.x & 0xFFFF0000u);
        s2 += __uint_as_float(u.y << 16);
        s3 += __uint_as_float(u.y & 0xFFFF0000u);
    }
    atomicAdd(&colsum[4 * cp + 0], s0);
    atomicAdd(&colsum[4 * cp + 1], s1);
    atomicAdd(&colsum[4 * cp + 2], s2);
    atomicAdd(&colsum[4 * cp + 3], s3);
}

// ---------- Ws[c][j] = Wo_w[j][c] / colsum[c] ----------
__global__ void k_prepWs(const float* __restrict__ Wo_w, const float* __restrict__ colsum,
                         float* __restrict__ Ws) {
    int i = blockIdx.x * 256 + threadIdx.x;   // 16384 total
    int c = i >> 6, j = i & 63;
    Ws[c * 64 + j] = Wo_w[j * NC + c] / colsum[c];
}

// ---------- out = expb @ Ws + b, LDS-tiled ----------
// j0 MUST be readfirstlane'd: makes Ws reads provably wave-uniform -> s_load.
__global__ void __launch_bounds__(256) k_out(const uint2* __restrict__ expb,
                                             const float* __restrict__ Ws,
                                             const float* __restrict__ Wo_b,
                                             float* __restrict__ out) {
    __shared__ unsigned tile[64][129];
    int n0 = blockIdx.x * 64;
    int rows = min(64, N_NODES - n0);
    int tid = threadIdx.x;

#pragma unroll
    for (int it = 0; it < 16; ++it) {
        int idx = tid + it * 256;          // 64 rows x 64 uint2
        int row = idx >> 6;                // wave-uniform per iteration
        int c4 = idx & 63;                 // lane-contiguous -> 512B bursts
        if (row < rows) {
            uint2 v = expb[(size_t)(n0 + row) * 64 + c4];
            tile[row][c4 * 2] = v.x;
            tile[row][c4 * 2 + 1] = v.y;
        }
    }
    __syncthreads();

    int nl = tid & 63;
    int j0 = __builtin_amdgcn_readfirstlane((tid >> 6) * 16);   // scalarize!
    int nr = min(nl, rows - 1);
    float acc[16];
#pragma unroll
    for (int jj = 0; jj < 16; ++jj) acc[jj] = 0.f;

#pragma unroll 2
    for (int cp = 0; cp < 128; ++cp) {     // 2 cols per iteration
        unsigned u = tile[nr][cp];
        float a0 = __uint_as_float(u << 16);
        float a1 = __uint_as_float(u & 0xFFFF0000u);
        const float* w0 = Ws + (2 * cp) * 64 + j0;   // wave-uniform -> s_load
        const float* w1 = w0 + 64;
#pragma unroll
        for (int jj = 0; jj < 16; ++jj)
            acc[jj] += a0 * w0[jj] + a1 * w1[jj];
    }

    if (nl < rows) {
        float* op = &out[(size_t)(n0 + nl) * DH + j0];
#pragma unroll
        for (int q = 0; q < 4; ++q) {
            float4 o;
            o.x = acc[q * 4 + 0] + Wo_b[j0 + q * 4 + 0];
            o.y = acc[q * 4 + 1] + Wo_b[j0 + q * 4 + 1];
            o.z = acc[q * 4 + 2] + Wo_b[j0 + q * 4 + 2];
            o.w = acc[q * 4 + 3] + Wo_b[j0 + q * 4 + 3];
            *(float4*)(op + q * 4) = o;
        }
    }
}

extern "C" void kernel_launch(void* const* d_in, const int* in_sizes, int n_in,
                              void* d_out, int out_size, void* d_ws, size_t ws_size,
                              hipStream_t stream) {
    const int*   ei   = (const int*)d_in[0];     // int32 from harness
    const float* x    = (const float*)d_in[1];
    const float* Ww   = (const float*)d_in[2];
    const float* Wb   = (const float*)d_in[3];
    const float* aw   = (const float*)d_in[4];
    const float* ab   = (const float*)d_in[5];
    const float* Wo_w = (const float*)d_in[6];
    const float* Wo_b = (const float*)d_in[7];
    float* out = (float*)d_out;

    char* p = (char*)d_ws;
    auto alloc = [&](size_t bytes) -> char* {
        char* q = p;
        p += (bytes + 255) & ~(size_t)255;
        return q;
    };
    uint2*    Wxb      = (uint2*)alloc((size_t)N_NODES * NC * 2);   // bf16 Wx copy
    uint2*    expb     = (uint2*)alloc((size_t)N_NODES * NC * 2);   // bf16 exp(agg)
    float*    Wt       = (float*)alloc((size_t)DX * NC * 4);
    float4*   Si4      = (float4*)alloc((size_t)N_NODES * 4 * 16);  // (si, e^si, e^.01si)
    float4*   Sj4      = (float4*)alloc((size_t)N_NODES * 4 * 16);
    int*      cnt      = (int*)alloc((size_t)N_NODES * 4);
    int*      rowstart = (int*)alloc((size_t)(N_NODES + 1) * 4);
    int*      csr_src  = (int*)alloc((size_t)(N_EDGES + N_NODES) * 4);
    unsigned* binned   = (unsigned*)alloc((size_t)N_EDGES * 4);
    float*    colsum   = (float*)alloc(NC * 4);
    float*    Ws       = (float*)alloc(NC * DH * 4);
    int*      bsum     = (int*)alloc(SCAN_BLOCKS * 4);
    int*      bcur     = (int*)alloc(SCAN_BLOCKS * 4);

    k_setup<<<(N_NODES + 255) / 256, 256, 0, stream>>>(Ww, Wt, cnt, colsum);
    k_gemm1<<<(N_NODES / 8 + 3) / 4, 256, 0, stream>>>(x, Wt, Wb, aw, ab, Wxb, Si4, Sj4);
    k_hist<<<1024, 256, 0, stream>>>(ei, cnt);
    k_blocksum<<<SCAN_BLOCKS, 256, 0, stream>>>(cnt, bsum);
    k_fill<<<SCAN_BLOCKS, 256, 0, stream>>>(cnt, bsum, rowstart, bcur, csr_src);
    k_bin<<<BIN_BLOCKS, 256, 0, stream>>>(ei, bcur, binned);
    k_scatter2<<<SCAN_BLOCKS, 256, 0, stream>>>(binned, rowstart, csr_src);
    k_aggregate<<<N_NODES / 4, 256, 0, stream>>>(rowstart, csr_src, Si4, Sj4, Wxb, expb);
    k_colsum<<<200, 256, 0, stream>>>(expb, colsum);
    k_prepWs<<<(NC * DH) / 256, 256, 0, stream>>>(Wo_w, colsum, Ws);
    k_out<<<(N_NODES + 63) / 64, 256, 0, stream>>>(expb, Ws, Wo_b, out);
}

// Round 13
// 401.377 us; speedup vs baseline: 1.2968x; 1.2968x over previous
//
#include <hip/hip_runtime.h>
#include <cfloat>

#define N_NODES 50000
#define N_EDGES 1600000
#define DX      128
#define DH      64
#define KH      4
#define NC      256                   // KH*DH
#define NEG_SLOPE 0.01f
#define SCAN_BLOCKS 196               // bucket count (dst>>8)
#define BIN_BLOCKS 250
#define BIN_CHUNK  6400               // 250*6400 = 1.6M edges exactly

// ---------- setup: zero bcnt/colsum, transpose Ww (256x128)->Wt(128x256) ----------
__global__ void k_setup(const float* __restrict__ Ww, float* __restrict__ Wt,
                        int* __restrict__ bcnt, float* __restrict__ colsum) {
    int i = blockIdx.x * 256 + threadIdx.x;   // grid 128 -> 32768 threads
    if (i < SCAN_BLOCKS) bcnt[i] = 0;
    if (i < NC) colsum[i] = 0.f;
    {
        int d = i >> 8, c = i & 255;
        Wt[d * NC + c] = Ww[c * DX + d];
    }
}

__device__ __forceinline__ unsigned pack_bf16(float a, float b) {
    unsigned ua = __float_as_uint(a), ub = __float_as_uint(b);
    ua = (ua + 0x7FFFu + ((ua >> 16) & 1u)) >> 16;          // RNE
    ub = (ub + 0x7FFFu + ((ub >> 16) & 1u)) & 0xFFFF0000u;
    return ua | ub;
}

// ---------- Wx GEMM + fused si/sj epilogue; writes bf16 copy for the gather ----------
__global__ void __launch_bounds__(256) k_gemm1(const float* __restrict__ x,
                                               const float* __restrict__ Wt,
                                               const float* __restrict__ Wb,
                                               const float* __restrict__ aw,
                                               const float* __restrict__ ab,
                                               uint2* __restrict__ Wxb,
                                               float* __restrict__ sic,
                                               float* __restrict__ sjc) {
    int wave = blockIdx.x * 4 + __builtin_amdgcn_readfirstlane(threadIdx.x >> 6);
    if (wave >= N_NODES / 8) return;           // 50000 % 8 == 0
    int lane = threadIdx.x & 63;
    int kh = lane >> 4, lq = lane & 15;
    int n0 = wave * 8;
    const float4* WtV = (const float4*)Wt;
    float acc[8][4];
#pragma unroll
    for (int r = 0; r < 8; ++r)
#pragma unroll
        for (int q = 0; q < 4; ++q) acc[r][q] = 0.f;

    for (int d = 0; d < DX; d += 4) {
        float xr[8][4];
#pragma unroll
        for (int r = 0; r < 8; ++r) {
            float4 v = *(const float4*)&x[(size_t)(n0 + r) * DX + d];
            xr[r][0] = v.x; xr[r][1] = v.y; xr[r][2] = v.z; xr[r][3] = v.w;
        }
#pragma unroll
        for (int q = 0; q < 4; ++q) {
            float4 wv = WtV[(size_t)(d + q) * 64 + lane];
#pragma unroll
            for (int r = 0; r < 8; ++r) {
                acc[r][0] += xr[r][q] * wv.x;
                acc[r][1] += xr[r][q] * wv.y;
                acc[r][2] += xr[r][q] * wv.z;
                acc[r][3] += xr[r][q] * wv.w;
            }
        }
    }
    float4 bias = ((const float4*)Wb)[lane];
    const float* awi = aw + kh * 2 * DH + lq * 4;
    const float* awj = awi + DH;
    float ai0 = awi[0], ai1 = awi[1], ai2 = awi[2], ai3 = awi[3];
    float aj0 = awj[0], aj1 = awj[1], aj2 = awj[2], aj3 = awj[3];
    float abk = ab[kh];
#pragma unroll
    for (int r = 0; r < 8; ++r) {
        float o0 = acc[r][0] + bias.x, o1 = acc[r][1] + bias.y;
        float o2 = acc[r][2] + bias.z, o3 = acc[r][3] + bias.w;
        uint2 pk; pk.x = pack_bf16(o0, o1); pk.y = pack_bf16(o2, o3);
        Wxb[(size_t)(n0 + r) * 64 + lane] = pk;
        float pi = o0 * ai0 + o1 * ai1 + o2 * ai2 + o3 * ai3;
        float pj = o0 * aj0 + o1 * aj1 + o2 * aj2 + o3 * aj3;
#pragma unroll
        for (int off = 8; off >= 1; off >>= 1) {
            pi += __shfl_xor(pi, off, 64);
            pj += __shfl_xor(pj, off, 64);
        }
        if (lq == 0) {
            sic[(n0 + r) * 4 + kh] = pi + abk;   // fold ab into dst-side score
            sjc[(n0 + r) * 4 + kh] = pj;
        }
    }
}

// ---------- bucket histogram: 196 bins, LDS-aggregated ----------
__global__ void __launch_bounds__(256) k_bhist(const int* __restrict__ ei,
                                               int* __restrict__ bcnt) {
    __shared__ int bh[SCAN_BLOCKS];
    int t = threadIdx.x;
    if (t < SCAN_BLOCKS) bh[t] = 0;
    __syncthreads();
    int e0 = blockIdx.x * BIN_CHUNK;
#pragma unroll 5
    for (int k = 0; k < BIN_CHUNK / 256; ++k) {
        int dst = ei[N_EDGES + e0 + t + k * 256];
        atomicAdd(&bh[dst >> 8], 1);
    }
    __syncthreads();
    if (t < SCAN_BLOCKS) atomicAdd(&bcnt[t], bh[t]);
}

// ---------- scan 196 bucket counts -> bbase (exclusive) + bcur ----------
__global__ void __launch_bounds__(256) k_scanb(const int* __restrict__ bcnt,
                                               int* __restrict__ bbase,
                                               int* __restrict__ bcur) {
    __shared__ int s[256];
    int t = threadIdx.x;
    int v = (t < SCAN_BLOCKS) ? bcnt[t] : 0;
    s[t] = v;
    __syncthreads();
#pragma unroll
    for (int off = 1; off < 256; off <<= 1) {
        int u = (t >= off) ? s[t - off] : 0;
        __syncthreads();
        s[t] += u;
        __syncthreads();
    }
    if (t < SCAN_BLOCKS) {
        int ex = s[t] - v;
        bbase[t] = ex;
        bcur[t] = ex;
    }
    if (t == SCAN_BLOCKS - 1) bbase[SCAN_BLOCKS] = s[t];   // = N_EDGES
}

// ---------- binning pass: edges -> 196 dst-buckets, dense chunked writes ----------
__global__ void __launch_bounds__(256) k_bin(const int* __restrict__ ei,
                                             int* __restrict__ bcur,
                                             unsigned* __restrict__ binned) {
    __shared__ int bh[SCAN_BLOCKS];   // count, then local cursor
    __shared__ int bb[SCAN_BLOCKS];   // reserved global base
    int t = threadIdx.x;
    if (t < SCAN_BLOCKS) bh[t] = 0;
    __syncthreads();
    int e0 = blockIdx.x * BIN_CHUNK;
#pragma unroll 5
    for (int k = 0; k < BIN_CHUNK / 256; ++k) {
        int dst = ei[N_EDGES + e0 + t + k * 256];
        atomicAdd(&bh[dst >> 8], 1);
    }
    __syncthreads();
    if (t < SCAN_BLOCKS) {
        bb[t] = atomicAdd(&bcur[t], bh[t]);
        bh[t] = 0;
    }
    __syncthreads();
#pragma unroll 5
    for (int k = 0; k < BIN_CHUNK / 256; ++k) {
        int e = e0 + t + k * 256;
        int src = ei[e];
        int dst = ei[N_EDGES + e];
        int b = dst >> 8;
        int lo = atomicAdd(&bh[b], 1);
        binned[bb[b] + lo] = (unsigned)src | ((unsigned)(dst & 255) << 16);   // src < 2^16
    }
}

// ---------- fused per-bucket: count dsts + scan + rowstart + self-loop + scatter ----------
__global__ void __launch_bounds__(256) k_scatter3(const unsigned* __restrict__ binned,
                                                  const int* __restrict__ bbase,
                                                  int* __restrict__ rowstart,
                                                  int* __restrict__ csr_src) {
    __shared__ int lcnt[256];
    __shared__ int lcur[256];
    __shared__ int s[256];
    int t = threadIdx.x, b = blockIdx.x;
    int e0 = bbase[b], e1 = bbase[b + 1];
    lcnt[t] = 0;
    __syncthreads();
    for (int i = e0 + t; i < e1; i += 256)
        atomicAdd(&lcnt[binned[i] >> 16], 1);
    __syncthreads();
    int v = lcnt[t];
    s[t] = v;
    __syncthreads();
#pragma unroll
    for (int off = 1; off < 256; off <<= 1) {
        int u = (t >= off) ? s[t - off] : 0;
        __syncthreads();
        s[t] += u;
        __syncthreads();
    }
    int d = b * 256 + t;
    int base_b = e0 + 256 * b;              // edges before bucket + self-loops before bucket
    if (d < N_NODES) {
        int rs = base_b + (s[t] - v) + t;   // + t self-loops within bucket
        rowstart[d] = rs;
        csr_src[rs] = d;                    // self-loop edge placed first
        lcur[t] = rs + 1;
    } else lcur[t] = 0;
    if (b == 0 && t == 0) rowstart[N_NODES] = N_EDGES + N_NODES;
    __syncthreads();
    for (int i = e0 + t; i < e1; i += 256) {
        unsigned u = binned[i];
        int pos = atomicAdd(&lcur[u >> 16], 1);
        csr_src[pos] = (int)(u & 0xFFFFu);
    }
}

// ---------- aggregation (R11-proven): per-edge exp, MLP x16, bf16 output ----------
__device__ __forceinline__ void edge_acc(unsigned gx, unsigned gy, float t, float sval,
                                         float& den, float& a0, float& a1, float& a2, float& a3) {
    float e = sval + t;
    e = (e >= 0.f) ? e : NEG_SLOPE * e;
    float ex = __expf(e);
    den += ex;
    a0 += ex * __uint_as_float(gx << 16);
    a1 += ex * __uint_as_float(gx & 0xFFFF0000u);
    a2 += ex * __uint_as_float(gy << 16);
    a3 += ex * __uint_as_float(gy & 0xFFFF0000u);
}

__global__ void __launch_bounds__(256) k_aggregate(const int* __restrict__ rowstart,
                                                   const int* __restrict__ csr_src,
                                                   const float* __restrict__ sic,
                                                   const float* __restrict__ sjc,
                                                   const uint2* __restrict__ Wxb,
                                                   uint2* __restrict__ expb) {
    int dst = blockIdx.x * 4 + (threadIdx.x >> 6);   // grid = 12500, exact
    int lane = threadIdx.x & 63;
    int kh = lane >> 4;
    int i0 = rowstart[dst], i1 = rowstart[dst + 1];
    float sval = sic[dst * 4 + kh];

    float den = 0.f, a0 = 0.f, a1 = 0.f, a2 = 0.f, a3 = 0.f;
    int i = i0;
    for (; i + 16 <= i1; i += 16) {
        int ss[16]; uint2 gg[16]; float tt[16];
#pragma unroll
        for (int u = 0; u < 16; ++u) ss[u] = csr_src[i + u];
#pragma unroll
        for (int u = 0; u < 16; ++u) gg[u] = Wxb[(size_t)ss[u] * 64 + lane];
#pragma unroll
        for (int u = 0; u < 16; ++u) tt[u] = sjc[ss[u] * 4 + kh];
#pragma unroll
        for (int u = 0; u < 16; ++u) edge_acc(gg[u].x, gg[u].y, tt[u], sval, den, a0, a1, a2, a3);
    }
    for (; i + 8 <= i1; i += 8) {
        int ss[8]; uint2 gg[8]; float tt[8];
#pragma unroll
        for (int u = 0; u < 8; ++u) ss[u] = csr_src[i + u];
#pragma unroll
        for (int u = 0; u < 8; ++u) gg[u] = Wxb[(size_t)ss[u] * 64 + lane];
#pragma unroll
        for (int u = 0; u < 8; ++u) tt[u] = sjc[ss[u] * 4 + kh];
#pragma unroll
        for (int u = 0; u < 8; ++u) edge_acc(gg[u].x, gg[u].y, tt[u], sval, den, a0, a1, a2, a3);
    }
    for (; i < i1; ++i) {
        int s = csr_src[i];
        uint2 g = Wxb[(size_t)s * 64 + lane];
        float t = sjc[s * 4 + kh];
        edge_acc(g.x, g.y, t, sval, den, a0, a1, a2, a3);
    }
    float r = 1.f / den;
    float e0 = __expf(a0 * r), e1 = __expf(a1 * r);
    float e2 = __expf(a2 * r), e3 = __expf(a3 * r);
    uint2 pk; pk.x = pack_bf16(e0, e1); pk.y = pack_bf16(e2, e3);
    expb[(size_t)dst * 64 + lane] = pk;          // bf16 exp(agg), cols 4l..4l+3
}

// ---------- column sums of exp(agg), bf16 input, 2 cols/thread ----------
__global__ void __launch_bounds__(256) k_colsum(const unsigned* __restrict__ expb,
                                                float* __restrict__ colsum) {
    int tid = threadIdx.x;
    int cp = tid & 127;            // uint index within row (cols 2cp, 2cp+1)
    int ro = tid >> 7;             // row parity
    int base = blockIdx.x * 196;
    int r1 = min(base + 196, N_NODES);
    float s0 = 0.f, s1 = 0.f;
    for (int r = base + ro; r < r1; r += 2) {
        unsigned u = expb[(size_t)r * 128 + cp];
        s0 += __uint_as_float(u << 16);
        s1 += __uint_as_float(u & 0xFFFF0000u);
    }
    atomicAdd(&colsum[2 * cp], s0);
    atomicAdd(&colsum[2 * cp + 1], s1);
}

// ---------- Ws[c][j] = Wo_w[j][c] / colsum[c] ----------
__global__ void k_prepWs(const float* __restrict__ Wo_w, const float* __restrict__ colsum,
                         float* __restrict__ Ws) {
    int i = blockIdx.x * 256 + threadIdx.x;   // 16384 total
    int c = i >> 6, j = i & 63;
    Ws[c * 64 + j] = Wo_w[j * NC + c] / colsum[c];
}

// ---------- out = expb @ Ws + b, LDS-tiled ----------
// j0 MUST be readfirstlane'd: makes Ws reads provably wave-uniform -> s_load.
__global__ void __launch_bounds__(256) k_out(const uint2* __restrict__ expb,
                                             const float* __restrict__ Ws,
                                             const float* __restrict__ Wo_b,
                                             float* __restrict__ out) {
    __shared__ unsigned tile[64][129];
    int n0 = blockIdx.x * 64;
    int rows = min(64, N_NODES - n0);
    int tid = threadIdx.x;

#pragma unroll
    for (int it = 0; it < 16; ++it) {
        int idx = tid + it * 256;          // 64 rows x 64 uint2
        int row = idx >> 6;                // wave-uniform per iteration
        int c4 = idx & 63;                 // lane-contiguous -> 512B bursts
        if (row < rows) {
            uint2 v = expb[(size_t)(n0 + row) * 64 + c4];
            tile[row][c4 * 2] = v.x;
            tile[row][c4 * 2 + 1] = v.y;
        }
    }
    __syncthreads();

    int nl = tid & 63;
    int j0 = __builtin_amdgcn_readfirstlane((tid >> 6) * 16);   // scalarize!
    int nr = min(nl, rows - 1);
    float acc[16];
#pragma unroll
    for (int jj = 0; jj < 16; ++jj) acc[jj] = 0.f;

#pragma unroll 2
    for (int cp = 0; cp < 128; ++cp) {     // 2 cols per iteration
        unsigned u = tile[nr][cp];
        float a0 = __uint_as_float(u << 16);
        float a1 = __uint_as_float(u & 0xFFFF0000u);
        const float* w0 = Ws + (2 * cp) * 64 + j0;   // wave-uniform -> s_load
        const float* w1 = w0 + 64;
#pragma unroll
        for (int jj = 0; jj < 16; ++jj)
            acc[jj] += a0 * w0[jj] + a1 * w1[jj];
    }

    if (nl < rows) {
        float* op = &out[(size_t)(n0 + nl) * DH + j0];
#pragma unroll
        for (int q = 0; q < 4; ++q) {
            float4 o;
            o.x = acc[q * 4 + 0] + Wo_b[j0 + q * 4 + 0];
            o.y = acc[q * 4 + 1] + Wo_b[j0 + q * 4 + 1];
            o.z = acc[q * 4 + 2] + Wo_b[j0 + q * 4 + 2];
            o.w = acc[q * 4 + 3] + Wo_b[j0 + q * 4 + 3];
            *(float4*)(op + q * 4) = o;
        }
    }
}

extern "C" void kernel_launch(void* const* d_in, const int* in_sizes, int n_in,
                              void* d_out, int out_size, void* d_ws, size_t ws_size,
                              hipStream_t stream) {
    const int*   ei   = (const int*)d_in[0];     // int32 from harness
    const float* x    = (const float*)d_in[1];
    const float* Ww   = (const float*)d_in[2];
    const float* Wb   = (const float*)d_in[3];
    const float* aw   = (const float*)d_in[4];
    const float* ab   = (const float*)d_in[5];
    const float* Wo_w = (const float*)d_in[6];
    const float* Wo_b = (const float*)d_in[7];
    float* out = (float*)d_out;

    char* p = (char*)d_ws;
    auto alloc = [&](size_t bytes) -> char* {
        char* q = p;
        p += (bytes + 255) & ~(size_t)255;
        return q;
    };
    uint2*    Wxb      = (uint2*)alloc((size_t)N_NODES * NC * 2);   // bf16 Wx copy
    uint2*    expb     = (uint2*)alloc((size_t)N_NODES * NC * 2);   // bf16 exp(agg)
    float*    Wt       = (float*)alloc((size_t)DX * NC * 4);
    float*    sic      = (float*)alloc((size_t)N_NODES * 4 * 4);
    float*    sjc      = (float*)alloc((size_t)N_NODES * 4 * 4);
    int*      rowstart = (int*)alloc((size_t)(N_NODES + 1) * 4);
    int*      csr_src  = (int*)alloc((size_t)(N_EDGES + N_NODES) * 4);
    unsigned* binned   = (unsigned*)alloc((size_t)N_EDGES * 4);
    float*    colsum   = (float*)alloc(NC * 4);
    float*    Ws       = (float*)alloc(NC * DH * 4);
    int*      bcnt     = (int*)alloc(SCAN_BLOCKS * 4);
    int*      bbase    = (int*)alloc((SCAN_BLOCKS + 1) * 4);
    int*      bcur     = (int*)alloc(SCAN_BLOCKS * 4);

    k_setup<<<128, 256, 0, stream>>>(Ww, Wt, bcnt, colsum);
    k_gemm1<<<(N_NODES / 8 + 3) / 4, 256, 0, stream>>>(x, Wt, Wb, aw, ab, Wxb, sic, sjc);
    k_bhist<<<BIN_BLOCKS, 256, 0, stream>>>(ei, bcnt);
    k_scanb<<<1, 256, 0, stream>>>(bcnt, bbase, bcur);
    k_bin<<<BIN_BLOCKS, 256, 0, stream>>>(ei, bcur, binned);
    k_scatter3<<<SCAN_BLOCKS, 256, 0, stream>>>(binned, bbase, rowstart, csr_src);
    k_aggregate<<<N_NODES / 4, 256, 0, stream>>>(rowstart, csr_src, sic, sjc, Wxb, expb);
    k_colsum<<<256, 256, 0, stream>>>((const unsigned*)expb, colsum);
    k_prepWs<<<(NC * DH) / 256, 256, 0, stream>>>(Wo_w, colsum, Ws);
    k_out<<<(N_NODES + 63) / 64, 256, 0, stream>>>(expb, Ws, Wo_b, out);
}